// Round 6
// baseline (124.189 us; speedup 1.0000x reference)
//
#include <hip/hip_runtime.h>
#include <stdint.h>

// LocallyConnected1d: out[b,c,o] = (1/8) * sum_{i<64,k<8} x[b,i,4o+k] * w[c,i,o,k]
// B=128, CIN=64, COUT=64, OUT_DIM=256, K=8, S=4, L=1028. fp32 in/out.
//
// R6 = R5 with K1's read loop fixed (R5 staged only 1/4 of the tile -> NaN).
// Two-phase: K1 transposes+converts w into bf16 workspace laid out exactly as
// the GEMM's LDS B-tile (bank-XOR baked in); K2 stages w via flat
// global_load_lds dwordx4 (zero VALU).
//  - K2 grid 1024 (q x b-quarter x c-half), 28 KB LDS -> 4 blocks/CU
//  - K1 grid 1024 (8-o tiles)
//  - matched writer/reader XCD swizzle: q-range [16k,16k+16) on XCD k in BOTH
//    kernels, so each XCD's 2.1 MB wb slab stays in its L2.

#define B_    128
#define CIN_  64
#define COUT_ 64
#define OD_   256
#define K_    8
#define L_    1028

// wb layout (bf16 elems): [q 128][ch 4][o_lo 2][c 64][gs 16][k 8], gs = i_loc ^ (c&7)
#define WB_PER_Q  65536
#define WB_PER_CH 16384

#define TSTR 70   // K1 tile row stride (elems): 35 dw -> ~2-way banks both phases
#define ALROW 12  // K2 A_lds row length (elems): 24 B rows -> conflict-free b64 reads

typedef __attribute__((ext_vector_type(8))) short bf16x8;
typedef __attribute__((ext_vector_type(4))) short short4v;
typedef __attribute__((ext_vector_type(4))) float floatx4;

__device__ __forceinline__ unsigned short f32_to_bf16(float f) {
    union { float f; uint32_t u; } v; v.f = f;
    uint32_t u = v.u;
    u += 0x7FFFu + ((u >> 16) & 1u);   // round-to-nearest-even
    return (unsigned short)(u >> 16);
}

// ---------------- K1: w fp32 -> wb bf16 (transpose + swizzle) ----------------
// grid 1024 = 8 xcd x 4 o-subtile x 8 c-tile x 4 i-chunk. 256 threads.
// Block handles 8 c x 16 i x 8 o x 8 k. XCD bit carries q-range (q0>>4 == bx&7).
__global__ __launch_bounds__(256, 4)
void lc1d_wprep(const float* __restrict__ w, unsigned short* __restrict__ wb) {
    __shared__ __align__(16) unsigned short tile[128 * TSTR];  // 17.9 KB

    const int tid  = threadIdx.x;
    const int bx   = blockIdx.x;
    const int xcd  = bx & 7;
    const int otL  = (bx >> 3) & 3;
    const int ot   = xcd * 4 + otL;     // o-tile of 8 -> q0 = ot*4 in [xcd*16, xcd*16+16)
    const int rest = bx >> 5;
    const int ct   = rest & 7;
    const int ch   = rest >> 3;         // 0..3
    const int c0   = ct * 8;
    const int i0   = ch * 16;
    const int o0   = ot * 8;
    const int q0   = ot * 4;

    // read: 128 rows (cL,iL) x 256 B contiguous (8 o x 8 k floats = 16 float4)
    #pragma unroll
    for (int it = 0; it < 8; ++it) {
        const int u   = it * 256 + tid;     // 0..2047
        const int t   = u & 15;             // float4 within row (16 per row)
        const int row = u >> 4;             // cL*16 + iL, 0..127
        const int iL  = row & 15;
        const int cL  = row >> 4;
        const float4 v = *(const float4*)(w +
            (size_t)((c0 + cL) * CIN_ + i0 + iL) * (OD_ * K_) + o0 * K_ + t * 4);
        ushort4 sv = make_ushort4(f32_to_bf16(v.x), f32_to_bf16(v.y),
                                  f32_to_bf16(v.z), f32_to_bf16(v.w));
        *(ushort4*)&tile[row * TSTR + t * 4] = sv;
    }
    __syncthreads();

    // write: granules (qL 0..3, o_lo, cL 0..7, gs 0..15) = 1024 -> 4/thread,
    // consecutive gs -> 256 B contiguous runs in wb.
    #pragma unroll
    for (int it = 0; it < 4; ++it) {
        const int u     = it * 256 + tid;
        const int gs    = u & 15;
        const int cL    = (u >> 4) & 7;
        const int o_lo  = (u >> 7) & 1;
        const int qL    = u >> 8;           // 0..3
        const int c     = c0 + cL;
        const int iL    = gs ^ (c & 7);     // bank-XOR baked into stored position
        const int o_loc = qL * 2 + o_lo;    // 0..7
        const bf16x8 vv = *(const bf16x8*)&tile[(cL * 16 + iL) * TSTR + o_loc * 8];
        const size_t dst = (size_t)(q0 + qL) * WB_PER_Q + (size_t)ch * WB_PER_CH
                         + ((size_t)((o_lo * 64 + c) * 16 + gs) << 3);
        *(bf16x8*)&wb[dst] = vv;
    }
}

// ---------------- K2: GEMM. block = (q, b-quarter, c-half), grid 1024 --------
__global__ __launch_bounds__(256, 4)
void lc1d_gemm(const float* __restrict__ x,
               const unsigned short* __restrict__ wb,
               float* __restrict__ out) {
    __shared__ __align__(16) unsigned short Bl[8192];            // 16 KB, flat wb slice
    __shared__ __align__(16) unsigned short Al[16 * 32 * ALROW]; // 12 KB

    const int tid = threadIdx.x;
    const int blk = blockIdx.x;
    // XCD k hosts q in [16k, 16k+16) — matches K1's writer placement.
    const int q     = (blk & 7) * 16 + ((blk >> 3) & 15);
    const int rest  = blk >> 7;          // 0..7
    const int chalf = rest & 1;
    const int bq    = rest >> 1;         // 0..3
    const int b0    = bq * 32;
    const int c0    = chalf * 32;

    const int wave = tid >> 6;
    const int lane = tid & 63;
    const int quad = lane >> 4;
    const int l16  = lane & 15;
    const int o_lo = wave & 1;           // which o of the pair
    const int ms   = wave >> 1;          // m-stripe (16 b rows)

    floatx4 acc[2];
    acc[0] = (floatx4){0.f, 0.f, 0.f, 0.f};
    acc[1] = (floatx4){0.f, 0.f, 0.f, 0.f};

    for (int ch = 0; ch < 4; ++ch) {
        // ---- w staging: flat DMA of wb[q][ch][o_lo][c0..c0+32)[gs][k] -> Bl ----
        // 16 KB total = 16 x (64 lanes x 16 B); zero VALU beyond lane*16.
        const char* wsrc = (const char*)(wb + (size_t)q * WB_PER_Q + (size_t)ch * WB_PER_CH);
        #pragma unroll
        for (int j = 0; j < 4; ++j) {
            const int off   = wave * 4096 + j * 1024;    // flat byte offset in Bl
            const int olo_d = off >> 13;                 // Bl o_lo stride 8192 B
            const int rem   = off & 8191;                // = cL*256 + gs*16 (+k*2)
            auto gp = (const __attribute__((address_space(1))) uint32_t*)
                      (wsrc + olo_d * 16384 + c0 * 256 + rem + lane * 16);
            auto lp = (__attribute__((address_space(3))) uint32_t*)((char*)&Bl[0] + off);
            __builtin_amdgcn_global_load_lds(gp, lp, 16, 0, 0);
        }

        // ---- x staging: rows (b 0..31, i 0..15) x 12 floats [8q, 8q+12) ----
        #pragma unroll
        for (int it = 0; it < 8; ++it) {
            const int u   = it * 256 + tid;
            const int t   = u & 3;           // float4 within row; t==3 masked
            const int row = u >> 2;          // 0..511
            const int iL  = row & 15;
            const int b   = row >> 4;        // 0..31
            if (t < 3) {
                const float4 v = *(const float4*)(x +
                    (size_t)((b0 + b) * CIN_ + ch * 16 + iL) * L_ + q * 8 + t * 4);
                ushort4 sv = make_ushort4(f32_to_bf16(v.x), f32_to_bf16(v.y),
                                          f32_to_bf16(v.z), f32_to_bf16(v.w));
                *(ushort4*)&Al[(iL * 32 + b) * ALROW + t * 4] = sv;
            }
        }
        __syncthreads();   // drains DMA (vmcnt) + LDS stores (lgkm)

        // ---- compute: 4 k-steps of 32 (i_loc = kt*4+quad, k = quad*8+j) ----
        #pragma unroll
        for (int kt = 0; kt < 4; ++kt) {
            const int i_l   = kt * 4 + quad;
            const int abase = (i_l * 32 + ms * 16 + l16) * ALROW + o_lo * 4;
            const short4v a_lo = *(const short4v*)&Al[abase];      // k 0..3 of window
            const short4v a_hi = *(const short4v*)&Al[abase + 4];  // k 4..7
            bf16x8 af;
            af[0] = a_lo[0]; af[1] = a_lo[1]; af[2] = a_lo[2]; af[3] = a_lo[3];
            af[4] = a_hi[0]; af[5] = a_hi[1]; af[6] = a_hi[2]; af[7] = a_hi[3];
            #pragma unroll
            for (int nt = 0; nt < 2; ++nt) {
                const int cL = nt * 16 + l16;                 // 0..31 within half
                const int gs = i_l ^ (cL & 7);                // c&7 == cL&7 (c0 % 32 == 0)
                const bf16x8 bf = *(const bf16x8*)&Bl[(size_t)(o_lo * 4096 + cL * 128 + gs * 8)];
                acc[nt] = __builtin_amdgcn_mfma_f32_16x16x32_bf16(af, bf, acc[nt], 0, 0, 0);
            }
        }
        __syncthreads();   // LDS reads done before next chunk overwrites
    }

    // ---- epilogue: D col=lane&15 (c), row=quad*4+reg (b); scale 1/sqrt(64) ----
    const int o_g = q * 2 + o_lo;
    #pragma unroll
    for (int nt = 0; nt < 2; ++nt) {
        const int c = c0 + nt * 16 + l16;
        #pragma unroll
        for (int r = 0; r < 4; ++r) {
            const int b = b0 + ms * 16 + quad * 4 + r;
            out[((size_t)b * COUT_ + c) * OD_ + o_g] = acc[nt][r] * 0.125f;
        }
    }
}

extern "C" void kernel_launch(void* const* d_in, const int* in_sizes, int n_in,
                              void* d_out, int out_size, void* d_ws, size_t ws_size,
                              hipStream_t stream) {
    const float* x = (const float*)d_in[0];     // (128, 64, 1028)
    const float* w = (const float*)d_in[1];     // (1, 64, 64, 256, 8)
    float* out = (float*)d_out;                 // (128, 64, 256)
    unsigned short* wb = (unsigned short*)d_ws; // 16.8 MB bf16 workspace

    hipLaunchKernelGGL(lc1d_wprep, dim3(1024), dim3(256), 0, stream, w, wb);
    hipLaunchKernelGGL(lc1d_gemm,  dim3(1024), dim3(256), 0, stream, x, wb, out);
}

// Round 7
// 116.794 us; speedup vs baseline: 1.0633x; 1.0633x over previous
//
#include <hip/hip_runtime.h>
#include <stdint.h>

// LocallyConnected1d: out[b,c,o] = (1/8) * sum_{i<64,k<8} x[b,i,4o+k] * w[c,i,o,k]
// B=128, CIN=64, COUT=64, OUT_DIM=256, K=8, S=4, L=1028. fp32 in/out.
//
// R7: FUSED single kernel. Block = (o-pair q, b-quarter), grid 512 (3/CU at
// 44 KB LDS), 256 threads. Per i-chunk (16): stage w fp32->bf16 into Bl with
// the bank-XOR baked into the LDS address (gs = i ^ (c&7)); stage x windows
// (12 floats, shared by the o-pair) into Al; 16 MFMA 16x16x32_bf16 per wave.
// All indexing pow2 (R3's %5 and conflict mistakes fixed). w read as 64 B
// contiguous runs (o-pair x 8k), fully coalesced.

#define B_    128
#define CIN_  64
#define COUT_ 64
#define OD_   256
#define K_    8
#define L_    1028

#define ALROW 12   // A_lds row length (elems): 24 B rows -> conflict-free b64 reads

typedef __attribute__((ext_vector_type(8))) short bf16x8;
typedef __attribute__((ext_vector_type(4))) short short4v;
typedef __attribute__((ext_vector_type(4))) float floatx4;

__device__ __forceinline__ unsigned short f32_to_bf16(float f) {
    union { float f; uint32_t u; } v; v.f = f;
    uint32_t u = v.u;
    u += 0x7FFFu + ((u >> 16) & 1u);   // round-to-nearest-even
    return (unsigned short)(u >> 16);
}

__global__ __launch_bounds__(256, 3)
void lc1d_fused(const float* __restrict__ x,
                const float* __restrict__ w,
                float* __restrict__ out) {
    // Bl[o_lo][c 64][gs 16][k 8] bf16, gs = i_loc ^ (c&7): 16384 el = 32 KB
    __shared__ __align__(16) unsigned short Bl[16384];
    // Al[(i 16)*32 + b][12]: 6144 el = 12 KB
    __shared__ __align__(16) unsigned short Al[16 * 32 * ALROW];

    const int tid = threadIdx.x;
    const int blk = blockIdx.x;
    // XCD k hosts q in [16k,16k+16): out-lines (8 q's) merge in one L2; the 4
    // b-quarter blocks of a q (128 apart) share its w slice in that L2.
    const int q  = (blk & 7) * 16 + ((blk >> 3) & 15);
    const int bq = blk >> 7;            // 0..3
    const int b0 = bq * 32;

    const int wave = tid >> 6;
    const int lane = tid & 63;
    const int quad = lane >> 4;
    const int l16  = lane & 15;
    const int o_lo = wave & 1;          // which o of the pair
    const int ms   = wave >> 1;         // m-stripe (16 b rows)

    floatx4 acc[4];
    #pragma unroll
    for (int nt = 0; nt < 4; ++nt) acc[nt] = (floatx4){0.f, 0.f, 0.f, 0.f};

    for (int ch = 0; ch < 4; ++ch) {
        const int i0 = ch * 16;

        // ---- w staging: 64 c x 16 i runs of 16 floats (o-pair x 8 k), 64 B
        // contiguous per run; 4096 float4 -> 16/thread. Swizzled bf16 store.
        #pragma unroll
        for (int it = 0; it < 16; ++it) {
            const int u   = it * 256 + tid;
            const int t   = u & 3;           // float4 within the 16-float run
            const int run = u >> 2;          // 0..1023
            const int iL  = run & 15;
            const int c   = run >> 4;        // 0..63 (global c)
            const float4 v = *(const float4*)(w +
                (size_t)(c * CIN_ + i0 + iL) * (OD_ * K_) + q * 16 + t * 4);
            ushort4 sv = make_ushort4(f32_to_bf16(v.x), f32_to_bf16(v.y),
                                      f32_to_bf16(v.z), f32_to_bf16(v.w));
            const int olo = t >> 1;          // floats 4t..4t+3 = (o_lo, k-half)
            const int kh  = t & 1;
            const int gs  = iL ^ (c & 7);    // bank-XOR baked into position
            *(ushort4*)&Bl[olo * 8192 + c * 128 + gs * 8 + kh * 4] = sv;
        }

        // ---- x staging: rows (b 0..31, i 0..15) x 12 floats [8q, 8q+12) ----
        #pragma unroll
        for (int it = 0; it < 8; ++it) {
            const int u   = it * 256 + tid;
            const int t   = u & 3;           // float4 within row; t==3 masked
            const int row = u >> 2;          // 0..511
            const int iL  = row & 15;
            const int b   = row >> 4;        // 0..31
            if (t < 3) {
                const float4 v = *(const float4*)(x +
                    (size_t)((b0 + b) * CIN_ + i0 + iL) * L_ + q * 8 + t * 4);
                ushort4 sv = make_ushort4(f32_to_bf16(v.x), f32_to_bf16(v.y),
                                          f32_to_bf16(v.z), f32_to_bf16(v.w));
                *(ushort4*)&Al[(iL * 32 + b) * ALROW + t * 4] = sv;
            }
        }
        __syncthreads();

        // ---- compute: 4 k-steps of 32 (i_loc = kt*4+quad, k = quad*8+j) ----
        #pragma unroll
        for (int kt = 0; kt < 4; ++kt) {
            const int i_l   = kt * 4 + quad;
            const int abase = (i_l * 32 + ms * 16 + l16) * ALROW + o_lo * 4;
            const short4v a_lo = *(const short4v*)&Al[abase];      // k 0..3
            const short4v a_hi = *(const short4v*)&Al[abase + 4];  // k 4..7
            bf16x8 af;
            af[0] = a_lo[0]; af[1] = a_lo[1]; af[2] = a_lo[2]; af[3] = a_lo[3];
            af[4] = a_hi[0]; af[5] = a_hi[1]; af[6] = a_hi[2]; af[7] = a_hi[3];
            #pragma unroll
            for (int nt = 0; nt < 4; ++nt) {
                const int c  = nt * 16 + l16;
                const int gs = i_l ^ (c & 7);
                const bf16x8 bf = *(const bf16x8*)&Bl[o_lo * 8192 + c * 128 + gs * 8];
                acc[nt] = __builtin_amdgcn_mfma_f32_16x16x32_bf16(af, bf, acc[nt], 0, 0, 0);
            }
        }
        __syncthreads();   // LDS reads done before next chunk overwrites
    }

    // ---- epilogue: D col=lane&15 (c), row=quad*4+reg (b); scale 1/sqrt(64) ----
    const int o_g = q * 2 + o_lo;
    #pragma unroll
    for (int nt = 0; nt < 4; ++nt) {
        const int c = nt * 16 + l16;
        #pragma unroll
        for (int r = 0; r < 4; ++r) {
            const int b = b0 + ms * 16 + quad * 4 + r;
            out[((size_t)b * COUT_ + c) * OD_ + o_g] = acc[nt][r] * 0.125f;
        }
    }
}

extern "C" void kernel_launch(void* const* d_in, const int* in_sizes, int n_in,
                              void* d_out, int out_size, void* d_ws, size_t ws_size,
                              hipStream_t stream) {
    const float* x = (const float*)d_in[0];   // (128, 64, 1028)
    const float* w = (const float*)d_in[1];   // (1, 64, 64, 256, 8)
    float* out = (float*)d_out;               // (128, 64, 256)
    hipLaunchKernelGGL(lc1d_fused, dim3(512), dim3(256), 0, stream, x, w, out);
}